// Round 6
// baseline (197.673 us; speedup 1.0000x reference)
//
#include <hip/hip_runtime.h>
#include <hip/hip_bf16.h>

#define LL 768
#define DD 1024
#define DP 128
#define HP 64
#define HH 128
#define NB 64

typedef float f32x4 __attribute__((ext_vector_type(4)));
typedef __bf16 bf16x8 __attribute__((ext_vector_type(8)));

// Exact-erf GELU via Abramowitz-Stegun 7.1.26 (abs err <= 1.5e-7), branchless.
// NOTE: tanh-form gelu remains unproven as the R2/R3 cause (R5 failed with
// THIS gelu -> the K=128 fold cluster was structurally broken). Keep exact.
__device__ __forceinline__ float gelu_exact(float x) {
    const float z = fabsf(x) * 0.70710678118654752f;
    const float t = __builtin_amdgcn_rcpf(__builtin_fmaf(0.3275911f, z, 1.0f));
    float p = __builtin_fmaf(t, 1.061405429f, -1.453152027f);
    p = __builtin_fmaf(t, p, 1.421413741f);
    p = __builtin_fmaf(t, p, -0.284496736f);
    p = __builtin_fmaf(t, p, 0.254829592f);
    p = p * t;
    const float e = __expf(-z * z);
    const float erfz = __builtin_fmaf(-p, e, 1.0f);
    const float phi = 0.5f * (1.0f + copysignf(erfz, x));
    return x * phi;
}

// ---------------------------------------------------------------------------
// Prep (R4-exact): xd = x @ W_down^T + b_down (f32), then
//   qb[j][p] = bf16(xd[j][p])          p<64
//   kf[i][p] = xd[i][64+p]             f32
//   A2[j][h] = sum_p W1[h][64+p]*q[j][p] + b1[h]
//   Bv[i][h] = sum_p W1[h][64+p]*k[i][p]
// ---------------------------------------------------------------------------
__global__ __launch_bounds__(256) void prep_kernel(
    const float* __restrict__ x, const float* __restrict__ Wd,
    const float* __restrict__ bd, const float* __restrict__ W1,
    const float* __restrict__ b1,
    __hip_bfloat16* __restrict__ qb, float* __restrict__ kf,
    float* __restrict__ A2, float* __restrict__ Bv)
{
    __shared__ __align__(16) float xs[8 * DD];
    __shared__ __align__(16) float xdl[8 * 128];
    const int tid = threadIdx.x;
    const int l0 = blockIdx.x * 8;

    const float4* xg = (const float4*)(x + (size_t)l0 * DD);
    float4* xs4 = (float4*)xs;
    for (int idx = tid; idx < 8 * DD / 4; idx += 256) xs4[idx] = xg[idx];
    __syncthreads();

    const int p = tid & 127;
    const int rg = tid >> 7;            // 0/1 -> rows rg*4 .. rg*4+3
    float acc[4] = {0.f, 0.f, 0.f, 0.f};
    #pragma unroll 8
    for (int c = 0; c < DD; c += 4) {
        float4 wv = *(const float4*)(Wd + (size_t)p * DD + c);
        #pragma unroll
        for (int rr = 0; rr < 4; ++rr) {
            float4 xv = *(const float4*)(xs + (rg * 4 + rr) * DD + c);
            acc[rr] += wv.x * xv.x + wv.y * xv.y + wv.z * xv.z + wv.w * xv.w;
        }
    }
    const float bdp = bd[p];
    #pragma unroll
    for (int rr = 0; rr < 4; ++rr) {
        const int row = rg * 4 + rr;
        const float v = acc[rr] + bdp;
        xdl[row * 128 + p] = v;
        if (p < HP) qb[(size_t)(l0 + row) * HP + p] = __float2bfloat16(v);
        else        kf[(size_t)(l0 + row) * HP + (p - HP)] = v;
    }
    __syncthreads();

    const int h = tid & 127;
    const int sel = tid >> 7;           // 0 -> A2 (q part), 1 -> Bv (k part)
    float a8[8] = {0.f,0.f,0.f,0.f,0.f,0.f,0.f,0.f};
    #pragma unroll
    for (int c = 0; c < HP; c += 4) {
        float4 wv = *(const float4*)(W1 + (size_t)h * DP + HP + c);
        #pragma unroll
        for (int row = 0; row < 8; ++row) {
            float4 xv = *(const float4*)(xdl + row * 128 + (sel ? HP : 0) + c);
            a8[row] += wv.x * xv.x + wv.y * xv.y + wv.z * xv.z + wv.w * xv.w;
        }
    }
    if (sel == 0) {
        const float bb = b1[h];
        #pragma unroll
        for (int row = 0; row < 8; ++row)
            A2[(size_t)(l0 + row) * HH + h] = a8[row] + bb;
    } else {
        #pragma unroll
        for (int row = 0; row < 8; ++row)
            Bv[(size_t)(l0 + row) * HH + h] = a8[row];
    }
}

// ---------------------------------------------------------------------------
// Main: R4 skeleton exactly, ONE change: W2 is no longer staged in LDS;
// GEMM2 B-fragments are built from the f32 W2 in global (L2-resident,
// 32 KB/block) with in-register bf16 convert -> bitwise-identical values.
// LDS 54272 -> 36864 B => 4 blocks/CU (was 2). All 3 barriers kept.
// ---------------------------------------------------------------------------
__global__ __launch_bounds__(256, 4) void main_kernel(
    const float* __restrict__ W1, const float* __restrict__ W2,
    const float* __restrict__ b2, const float* __restrict__ lng,
    const float* __restrict__ lnb,
    const __hip_bfloat16* __restrict__ qb, const float* __restrict__ kf,
    const float* __restrict__ A2, const float* __restrict__ Bv,
    float* __restrict__ out)
{
    // [0, 18432) Mi[128][72] bf16 ; [18432, 36864) qt[128][72] bf16
    // hbuf[128][136] bf16 (34816 B) reuses [0,34816) after GEMM1 barrier
    __shared__ __align__(16) unsigned char smem[36864];
    __bf16* Mi   = (__bf16*)smem;
    __bf16* qt   = (__bf16*)(smem + 18432);
    __bf16* hbuf = (__bf16*)smem;

    const int tid  = threadIdx.x;
    const int lane = tid & 63;
    const int w    = tid >> 6;          // wave id 0..3
    const int lo   = lane & 15;
    const int g4   = lane >> 4;
    const int i    = blockIdx.y;
    const int j0   = blockIdx.x * 128;

    // ---- stage Mi = bf16(W1a * k_i)
    {
        const int hrow = tid >> 1;
        const int pb = (tid & 1) * 32;
        const float* w1r = W1 + (size_t)hrow * DP + pb;
        const float* kfr = kf + (size_t)i * HP + pb;
        #pragma unroll
        for (int m = 0; m < 4; ++m) {
            float4 w0 = *(const float4*)(w1r + m * 8);
            float4 w1v = *(const float4*)(w1r + m * 8 + 4);
            float4 k0 = *(const float4*)(kfr + m * 8);
            float4 k1 = *(const float4*)(kfr + m * 8 + 4);
            bf16x8 t;
            t[0] = (__bf16)(w0.x * k0.x); t[1] = (__bf16)(w0.y * k0.y);
            t[2] = (__bf16)(w0.z * k0.z); t[3] = (__bf16)(w0.w * k0.w);
            t[4] = (__bf16)(w1v.x * k1.x); t[5] = (__bf16)(w1v.y * k1.y);
            t[6] = (__bf16)(w1v.z * k1.z); t[7] = (__bf16)(w1v.w * k1.w);
            *(bf16x8*)&Mi[hrow * 72 + pb + m * 8] = t;
        }
    }
    // ---- stage qt (bf16 bit-copy)
    {
        const int jl = tid >> 1;
        const int pb = (tid & 1) * 32;
        const unsigned short* src = (const unsigned short*)qb + (size_t)(j0 + jl) * HP + pb;
        #pragma unroll
        for (int m = 0; m < 4; ++m) {
            uint4 v = *(const uint4*)(src + m * 8);
            *(uint4*)&qt[jl * 72 + pb + m * 8] = v;
        }
    }
    // per-lane constants
    float BvR[8], lgR[8], lbR[8];
    #pragma unroll
    for (int t = 0; t < 8; ++t) {
        const int h = t * 16 + lo;
        BvR[t] = Bv[(size_t)i * HH + h];
        lgR[t] = lng[h];
        lbR[t] = lnb[h];
    }
    float b2R[4];
    #pragma unroll
    for (int t = 0; t < 4; ++t) b2R[t] = b2[t * 16 + lo];

    __syncthreads();

    // ---- GEMM1: wave w owns rows [32w, 32w+32), all 128 h cols
    f32x4 acc[2][8];
    #pragma unroll
    for (int a = 0; a < 2; ++a)
        #pragma unroll
        for (int b = 0; b < 8; ++b)
            #pragma unroll
            for (int e = 0; e < 4; ++e) acc[a][b][e] = 0.f;

    #pragma unroll
    for (int kk = 0; kk < 2; ++kk) {
        bf16x8 af[2];
        #pragma unroll
        for (int mt = 0; mt < 2; ++mt) {
            const int jl = 32 * w + mt * 16 + lo;
            af[mt] = *(const bf16x8*)&qt[jl * 72 + kk * 32 + g4 * 8];
        }
        #pragma unroll
        for (int nt = 0; nt < 8; ++nt) {
            const int h = nt * 16 + lo;
            bf16x8 bfr = *(const bf16x8*)&Mi[h * 72 + kk * 32 + g4 * 8];
            #pragma unroll
            for (int mt = 0; mt < 2; ++mt)
                acc[mt][nt] = __builtin_amdgcn_mfma_f32_16x16x32_bf16(af[mt], bfr, acc[mt][nt], 0, 0, 0);
        }
    }

    __syncthreads();   // all waves done reading Mi/qt; hbuf may overwrite

    // ---- epilogue: v = acc + A2[j][h] - Bv[i][h]; gelu_exact; LN -> hbuf
    #pragma unroll
    for (int mt = 0; mt < 2; ++mt) {
        float s[4] = {0.f,0.f,0.f,0.f}, ss[4] = {0.f,0.f,0.f,0.f};
        #pragma unroll
        for (int nt = 0; nt < 8; ++nt) {
            const int h = nt * 16 + lo;
            #pragma unroll
            for (int r = 0; r < 4; ++r) {
                const int j = j0 + 32 * w + mt * 16 + g4 * 4 + r;
                float v = acc[mt][nt][r] + A2[(size_t)j * HH + h] - BvR[nt];
                float g = gelu_exact(v);
                acc[mt][nt][r] = g;
                s[r] += g; ss[r] += g * g;
            }
        }
        #pragma unroll
        for (int r = 0; r < 4; ++r) {
            float sv = s[r], sq = ss[r];
            #pragma unroll
            for (int m = 1; m < 16; m <<= 1) {
                sv += __shfl_xor(sv, m);
                sq += __shfl_xor(sq, m);
            }
            const float mu  = sv * (1.0f / 128.0f);
            const float var = sq * (1.0f / 128.0f) - mu * mu;
            const float rstd = rsqrtf(var + 1e-5f);
            const int jl = 32 * w + mt * 16 + g4 * 4 + r;
            #pragma unroll
            for (int nt = 0; nt < 8; ++nt) {
                const float hv = (acc[mt][nt][r] - mu) * rstd * lgR[nt] + lbR[nt];
                hbuf[jl * 136 + nt * 16 + lo] = (__bf16)hv;
            }
        }
    }
    __syncthreads();

    // ---- GEMM2: Out[128][64] = hbuf[128][128] @ bf16(W2)^T
    //      B-fragments read from f32 W2 in global (L2-resident) + cvt.
    f32x4 acc2[2][4];
    #pragma unroll
    for (int a = 0; a < 2; ++a)
        #pragma unroll
        for (int b = 0; b < 4; ++b)
            #pragma unroll
            for (int e = 0; e < 4; ++e) acc2[a][b][e] = 0.f;

    #pragma unroll
    for (int kk = 0; kk < 4; ++kk) {
        bf16x8 af[2];
        #pragma unroll
        for (int mt = 0; mt < 2; ++mt) {
            const int jl = 32 * w + mt * 16 + lo;
            af[mt] = *(const bf16x8*)&hbuf[jl * 136 + kk * 32 + g4 * 8];
        }
        #pragma unroll
        for (int nt = 0; nt < 4; ++nt) {
            const float* wsrc = W2 + (size_t)(nt * 16 + lo) * HH + kk * 32 + g4 * 8;
            float4 v0 = *(const float4*)(wsrc);
            float4 v1 = *(const float4*)(wsrc + 4);
            bf16x8 bfr;
            bfr[0] = (__bf16)v0.x; bfr[1] = (__bf16)v0.y;
            bfr[2] = (__bf16)v0.z; bfr[3] = (__bf16)v0.w;
            bfr[4] = (__bf16)v1.x; bfr[5] = (__bf16)v1.y;
            bfr[6] = (__bf16)v1.z; bfr[7] = (__bf16)v1.w;
            #pragma unroll
            for (int mt = 0; mt < 2; ++mt)
                acc2[mt][nt] = __builtin_amdgcn_mfma_f32_16x16x32_bf16(af[mt], bfr, acc2[mt][nt], 0, 0, 0);
        }
    }

    // ---- store
    #pragma unroll
    for (int mt = 0; mt < 2; ++mt) {
        #pragma unroll
        for (int r = 0; r < 4; ++r) {
            const int j = j0 + 32 * w + mt * 16 + g4 * 4 + r;
            const size_t base = ((size_t)i * LL + j) * NB;
            #pragma unroll
            for (int nt = 0; nt < 4; ++nt)
                out[base + nt * 16 + lo] = acc2[mt][nt][r] + b2R[nt];
        }
    }
}

extern "C" void kernel_launch(void* const* d_in, const int* in_sizes, int n_in,
                              void* d_out, int out_size, void* d_ws, size_t ws_size,
                              hipStream_t stream) {
    const float* x   = (const float*)d_in[0];
    const float* Wd  = (const float*)d_in[1];
    const float* bd  = (const float*)d_in[2];
    const float* W1  = (const float*)d_in[3];
    const float* b1  = (const float*)d_in[4];
    const float* lng = (const float*)d_in[5];
    const float* lnb = (const float*)d_in[6];
    const float* W2  = (const float*)d_in[7];
    const float* b2  = (const float*)d_in[8];
    float* out = (float*)d_out;

    char* ws = (char*)d_ws;
    __hip_bfloat16* qb = (__hip_bfloat16*)ws;            //  98304 B
    float* kf = (float*)(ws + 98304);                    // 196608 B
    float* A2 = (float*)(ws + 294912);                   // 393216 B
    float* Bv = (float*)(ws + 688128);                   // 393216 B

    prep_kernel<<<96, 256, 0, stream>>>(x, Wd, bd, W1, b1, qb, kf, A2, Bv);
    dim3 grid(6, 768);
    main_kernel<<<grid, 256, 0, stream>>>(W1, W2, b2, lng, lnb, qb, kf, A2, Bv, out);
}

// Round 7
// 187.174 us; speedup vs baseline: 1.0561x; 1.0561x over previous
//
#include <hip/hip_runtime.h>
#include <hip/hip_bf16.h>

#define LL 768
#define DD 1024
#define DP 128
#define HP 64
#define HH 128
#define NB 64

typedef float f32x4 __attribute__((ext_vector_type(4)));
typedef __bf16 bf16x8 __attribute__((ext_vector_type(8)));

// Exact-erf GELU via Abramowitz-Stegun 7.1.26 (abs err <= 1.5e-7), branchless.
__device__ __forceinline__ float gelu_exact(float x) {
    const float z = fabsf(x) * 0.70710678118654752f;
    const float t = __builtin_amdgcn_rcpf(__builtin_fmaf(0.3275911f, z, 1.0f));
    float p = __builtin_fmaf(t, 1.061405429f, -1.453152027f);
    p = __builtin_fmaf(t, p, 1.421413741f);
    p = __builtin_fmaf(t, p, -0.284496736f);
    p = __builtin_fmaf(t, p, 0.254829592f);
    p = p * t;
    const float e = __expf(-z * z);
    const float erfz = __builtin_fmaf(-p, e, 1.0f);
    const float phi = 0.5f * (1.0f + copysignf(erfz, x));
    return x * phi;
}

// ---------------------------------------------------------------------------
// Prep (R4-exact): xd = x @ W_down^T + b_down (f32), then
//   qb[j][p] = bf16(xd[j][p])          p<64
//   kf[i][p] = xd[i][64+p]             f32
//   A2[j][h] = sum_p W1[h][64+p]*q[j][p] + b1[h]
//   Bv[i][h] = sum_p W1[h][64+p]*k[i][p]
// ---------------------------------------------------------------------------
__global__ __launch_bounds__(256) void prep_kernel(
    const float* __restrict__ x, const float* __restrict__ Wd,
    const float* __restrict__ bd, const float* __restrict__ W1,
    const float* __restrict__ b1,
    __hip_bfloat16* __restrict__ qb, float* __restrict__ kf,
    float* __restrict__ A2, float* __restrict__ Bv)
{
    __shared__ __align__(16) float xs[8 * DD];
    __shared__ __align__(16) float xdl[8 * 128];
    const int tid = threadIdx.x;
    const int l0 = blockIdx.x * 8;

    const float4* xg = (const float4*)(x + (size_t)l0 * DD);
    float4* xs4 = (float4*)xs;
    for (int idx = tid; idx < 8 * DD / 4; idx += 256) xs4[idx] = xg[idx];
    __syncthreads();

    const int p = tid & 127;
    const int rg = tid >> 7;            // 0/1 -> rows rg*4 .. rg*4+3
    float acc[4] = {0.f, 0.f, 0.f, 0.f};
    #pragma unroll 8
    for (int c = 0; c < DD; c += 4) {
        float4 wv = *(const float4*)(Wd + (size_t)p * DD + c);
        #pragma unroll
        for (int rr = 0; rr < 4; ++rr) {
            float4 xv = *(const float4*)(xs + (rg * 4 + rr) * DD + c);
            acc[rr] += wv.x * xv.x + wv.y * xv.y + wv.z * xv.z + wv.w * xv.w;
        }
    }
    const float bdp = bd[p];
    #pragma unroll
    for (int rr = 0; rr < 4; ++rr) {
        const int row = rg * 4 + rr;
        const float v = acc[rr] + bdp;
        xdl[row * 128 + p] = v;
        if (p < HP) qb[(size_t)(l0 + row) * HP + p] = __float2bfloat16(v);
        else        kf[(size_t)(l0 + row) * HP + (p - HP)] = v;
    }
    __syncthreads();

    const int h = tid & 127;
    const int sel = tid >> 7;           // 0 -> A2 (q part), 1 -> Bv (k part)
    float a8[8] = {0.f,0.f,0.f,0.f,0.f,0.f,0.f,0.f};
    #pragma unroll
    for (int c = 0; c < HP; c += 4) {
        float4 wv = *(const float4*)(W1 + (size_t)h * DP + HP + c);
        #pragma unroll
        for (int row = 0; row < 8; ++row) {
            float4 xv = *(const float4*)(xdl + row * 128 + (sel ? HP : 0) + c);
            a8[row] += wv.x * xv.x + wv.y * xv.y + wv.z * xv.z + wv.w * xv.w;
        }
    }
    if (sel == 0) {
        const float bb = b1[h];
        #pragma unroll
        for (int row = 0; row < 8; ++row)
            A2[(size_t)(l0 + row) * HH + h] = a8[row] + bb;
    } else {
        #pragma unroll
        for (int row = 0; row < 8; ++row)
            Bv[(size_t)(l0 + row) * HH + h] = a8[row];
    }
}

// ---------------------------------------------------------------------------
// Main: R6 structure (LDS 36864 -> 4 blocks/CU; GEMM2 B from global f32 W2
// + in-reg cvt) but with R4's plain __launch_bounds__(256).
// R6's (256,4) clamp forced VGPR 64 -> 16-f32/thread scratch spill
// (WRITE_SIZE +73728 KB, FETCH +36 MB) and a 23% regression.
// ---------------------------------------------------------------------------
__global__ __launch_bounds__(256) void main_kernel(
    const float* __restrict__ W1, const float* __restrict__ W2,
    const float* __restrict__ b2, const float* __restrict__ lng,
    const float* __restrict__ lnb,
    const __hip_bfloat16* __restrict__ qb, const float* __restrict__ kf,
    const float* __restrict__ A2, const float* __restrict__ Bv,
    float* __restrict__ out)
{
    // [0, 18432) Mi[128][72] bf16 ; [18432, 36864) qt[128][72] bf16
    // hbuf[128][136] bf16 (34816 B) reuses [0,34816) after GEMM1 barrier
    __shared__ __align__(16) unsigned char smem[36864];
    __bf16* Mi   = (__bf16*)smem;
    __bf16* qt   = (__bf16*)(smem + 18432);
    __bf16* hbuf = (__bf16*)smem;

    const int tid  = threadIdx.x;
    const int lane = tid & 63;
    const int w    = tid >> 6;          // wave id 0..3
    const int lo   = lane & 15;
    const int g4   = lane >> 4;
    const int i    = blockIdx.y;
    const int j0   = blockIdx.x * 128;

    // ---- stage Mi = bf16(W1a * k_i)
    {
        const int hrow = tid >> 1;
        const int pb = (tid & 1) * 32;
        const float* w1r = W1 + (size_t)hrow * DP + pb;
        const float* kfr = kf + (size_t)i * HP + pb;
        #pragma unroll
        for (int m = 0; m < 4; ++m) {
            float4 w0 = *(const float4*)(w1r + m * 8);
            float4 w1v = *(const float4*)(w1r + m * 8 + 4);
            float4 k0 = *(const float4*)(kfr + m * 8);
            float4 k1 = *(const float4*)(kfr + m * 8 + 4);
            bf16x8 t;
            t[0] = (__bf16)(w0.x * k0.x); t[1] = (__bf16)(w0.y * k0.y);
            t[2] = (__bf16)(w0.z * k0.z); t[3] = (__bf16)(w0.w * k0.w);
            t[4] = (__bf16)(w1v.x * k1.x); t[5] = (__bf16)(w1v.y * k1.y);
            t[6] = (__bf16)(w1v.z * k1.z); t[7] = (__bf16)(w1v.w * k1.w);
            *(bf16x8*)&Mi[hrow * 72 + pb + m * 8] = t;
        }
    }
    // ---- stage qt (bf16 bit-copy)
    {
        const int jl = tid >> 1;
        const int pb = (tid & 1) * 32;
        const unsigned short* src = (const unsigned short*)qb + (size_t)(j0 + jl) * HP + pb;
        #pragma unroll
        for (int m = 0; m < 4; ++m) {
            uint4 v = *(const uint4*)(src + m * 8);
            *(uint4*)&qt[jl * 72 + pb + m * 8] = v;
        }
    }
    // per-lane constants
    float BvR[8], lgR[8], lbR[8];
    #pragma unroll
    for (int t = 0; t < 8; ++t) {
        const int h = t * 16 + lo;
        BvR[t] = Bv[(size_t)i * HH + h];
        lgR[t] = lng[h];
        lbR[t] = lnb[h];
    }
    float b2R[4];
    #pragma unroll
    for (int t = 0; t < 4; ++t) b2R[t] = b2[t * 16 + lo];

    __syncthreads();

    // ---- GEMM1: wave w owns rows [32w, 32w+32), all 128 h cols
    f32x4 acc[2][8];
    #pragma unroll
    for (int a = 0; a < 2; ++a)
        #pragma unroll
        for (int b = 0; b < 8; ++b)
            #pragma unroll
            for (int e = 0; e < 4; ++e) acc[a][b][e] = 0.f;

    #pragma unroll
    for (int kk = 0; kk < 2; ++kk) {
        bf16x8 af[2];
        #pragma unroll
        for (int mt = 0; mt < 2; ++mt) {
            const int jl = 32 * w + mt * 16 + lo;
            af[mt] = *(const bf16x8*)&qt[jl * 72 + kk * 32 + g4 * 8];
        }
        #pragma unroll
        for (int nt = 0; nt < 8; ++nt) {
            const int h = nt * 16 + lo;
            bf16x8 bfr = *(const bf16x8*)&Mi[h * 72 + kk * 32 + g4 * 8];
            #pragma unroll
            for (int mt = 0; mt < 2; ++mt)
                acc[mt][nt] = __builtin_amdgcn_mfma_f32_16x16x32_bf16(af[mt], bfr, acc[mt][nt], 0, 0, 0);
        }
    }

    __syncthreads();   // all waves done reading Mi/qt; hbuf may overwrite

    // ---- epilogue: v = acc + A2[j][h] - Bv[i][h]; gelu_exact; LN -> hbuf
    #pragma unroll
    for (int mt = 0; mt < 2; ++mt) {
        float s[4] = {0.f,0.f,0.f,0.f}, ss[4] = {0.f,0.f,0.f,0.f};
        #pragma unroll
        for (int nt = 0; nt < 8; ++nt) {
            const int h = nt * 16 + lo;
            #pragma unroll
            for (int r = 0; r < 4; ++r) {
                const int j = j0 + 32 * w + mt * 16 + g4 * 4 + r;
                float v = acc[mt][nt][r] + A2[(size_t)j * HH + h] - BvR[nt];
                float g = gelu_exact(v);
                acc[mt][nt][r] = g;
                s[r] += g; ss[r] += g * g;
            }
        }
        #pragma unroll
        for (int r = 0; r < 4; ++r) {
            float sv = s[r], sq = ss[r];
            #pragma unroll
            for (int m = 1; m < 16; m <<= 1) {
                sv += __shfl_xor(sv, m);
                sq += __shfl_xor(sq, m);
            }
            const float mu  = sv * (1.0f / 128.0f);
            const float var = sq * (1.0f / 128.0f) - mu * mu;
            const float rstd = rsqrtf(var + 1e-5f);
            const int jl = 32 * w + mt * 16 + g4 * 4 + r;
            #pragma unroll
            for (int nt = 0; nt < 8; ++nt) {
                const float hv = (acc[mt][nt][r] - mu) * rstd * lgR[nt] + lbR[nt];
                hbuf[jl * 136 + nt * 16 + lo] = (__bf16)hv;
            }
        }
    }
    __syncthreads();

    // ---- GEMM2: Out[128][64] = hbuf[128][128] @ bf16(W2)^T
    //      B-fragments read from f32 W2 in global (L2-resident) + cvt.
    f32x4 acc2[2][4];
    #pragma unroll
    for (int a = 0; a < 2; ++a)
        #pragma unroll
        for (int b = 0; b < 4; ++b)
            #pragma unroll
            for (int e = 0; e < 4; ++e) acc2[a][b][e] = 0.f;

    #pragma unroll
    for (int kk = 0; kk < 4; ++kk) {
        bf16x8 af[2];
        #pragma unroll
        for (int mt = 0; mt < 2; ++mt) {
            const int jl = 32 * w + mt * 16 + lo;
            af[mt] = *(const bf16x8*)&hbuf[jl * 136 + kk * 32 + g4 * 8];
        }
        #pragma unroll
        for (int nt = 0; nt < 4; ++nt) {
            const float* wsrc = W2 + (size_t)(nt * 16 + lo) * HH + kk * 32 + g4 * 8;
            float4 v0 = *(const float4*)(wsrc);
            float4 v1 = *(const float4*)(wsrc + 4);
            bf16x8 bfr;
            bfr[0] = (__bf16)v0.x; bfr[1] = (__bf16)v0.y;
            bfr[2] = (__bf16)v0.z; bfr[3] = (__bf16)v0.w;
            bfr[4] = (__bf16)v1.x; bfr[5] = (__bf16)v1.y;
            bfr[6] = (__bf16)v1.z; bfr[7] = (__bf16)v1.w;
            #pragma unroll
            for (int mt = 0; mt < 2; ++mt)
                acc2[mt][nt] = __builtin_amdgcn_mfma_f32_16x16x32_bf16(af[mt], bfr, acc2[mt][nt], 0, 0, 0);
        }
    }

    // ---- store
    #pragma unroll
    for (int mt = 0; mt < 2; ++mt) {
        #pragma unroll
        for (int r = 0; r < 4; ++r) {
            const int j = j0 + 32 * w + mt * 16 + g4 * 4 + r;
            const size_t base = ((size_t)i * LL + j) * NB;
            #pragma unroll
            for (int nt = 0; nt < 4; ++nt)
                out[base + nt * 16 + lo] = acc2[mt][nt][r] + b2R[nt];
        }
    }
}

extern "C" void kernel_launch(void* const* d_in, const int* in_sizes, int n_in,
                              void* d_out, int out_size, void* d_ws, size_t ws_size,
                              hipStream_t stream) {
    const float* x   = (const float*)d_in[0];
    const float* Wd  = (const float*)d_in[1];
    const float* bd  = (const float*)d_in[2];
    const float* W1  = (const float*)d_in[3];
    const float* b1  = (const float*)d_in[4];
    const float* lng = (const float*)d_in[5];
    const float* lnb = (const float*)d_in[6];
    const float* W2  = (const float*)d_in[7];
    const float* b2  = (const float*)d_in[8];
    float* out = (float*)d_out;

    char* ws = (char*)d_ws;
    __hip_bfloat16* qb = (__hip_bfloat16*)ws;            //  98304 B
    float* kf = (float*)(ws + 98304);                    // 196608 B
    float* A2 = (float*)(ws + 294912);                   // 393216 B
    float* Bv = (float*)(ws + 688128);                   // 393216 B

    prep_kernel<<<96, 256, 0, stream>>>(x, Wd, bd, W1, b1, qb, kf, A2, Bv);
    dim3 grid(6, 768);
    main_kernel<<<grid, 256, 0, stream>>>(W1, W2, b2, lng, lnb, qb, kf, A2, Bv, out);
}

// Round 8
// 159.944 us; speedup vs baseline: 1.2359x; 1.1702x over previous
//
#include <hip/hip_runtime.h>
#include <hip/hip_bf16.h>

#define LL 768
#define DD 1024
#define DP 128
#define HP 64
#define HH 128
#define NB 64

typedef float f32x4 __attribute__((ext_vector_type(4)));
typedef __bf16 bf16x8 __attribute__((ext_vector_type(8)));

// Exact-erf GELU via Abramowitz-Stegun 7.1.26 (abs err <= 1.5e-7), branchless.
__device__ __forceinline__ float gelu_exact(float x) {
    const float z = fabsf(x) * 0.70710678118654752f;
    const float t = __builtin_amdgcn_rcpf(__builtin_fmaf(0.3275911f, z, 1.0f));
    float p = __builtin_fmaf(t, 1.061405429f, -1.453152027f);
    p = __builtin_fmaf(t, p, 1.421413741f);
    p = __builtin_fmaf(t, p, -0.284496736f);
    p = __builtin_fmaf(t, p, 0.254829592f);
    p = p * t;
    const float e = __expf(-z * z);
    const float erfz = __builtin_fmaf(-p, e, 1.0f);
    const float phi = 0.5f * (1.0f + copysignf(erfz, x));
    return x * phi;
}

// ---------------------------------------------------------------------------
// Prep (R4-exact): xd = x @ W_down^T + b_down (f32), then
//   qb[j][p] = bf16(xd[j][p])          p<64
//   kf[i][p] = xd[i][64+p]             f32
//   A2[j][h] = sum_p W1[h][64+p]*q[j][p] + b1[h]
//   Bv[i][h] = sum_p W1[h][64+p]*k[i][p]
// ---------------------------------------------------------------------------
__global__ __launch_bounds__(256) void prep_kernel(
    const float* __restrict__ x, const float* __restrict__ Wd,
    const float* __restrict__ bd, const float* __restrict__ W1,
    const float* __restrict__ b1,
    __hip_bfloat16* __restrict__ qb, float* __restrict__ kf,
    float* __restrict__ A2, float* __restrict__ Bv)
{
    __shared__ __align__(16) float xs[8 * DD];
    __shared__ __align__(16) float xdl[8 * 128];
    const int tid = threadIdx.x;
    const int l0 = blockIdx.x * 8;

    const float4* xg = (const float4*)(x + (size_t)l0 * DD);
    float4* xs4 = (float4*)xs;
    for (int idx = tid; idx < 8 * DD / 4; idx += 256) xs4[idx] = xg[idx];
    __syncthreads();

    const int p = tid & 127;
    const int rg = tid >> 7;            // 0/1 -> rows rg*4 .. rg*4+3
    float acc[4] = {0.f, 0.f, 0.f, 0.f};
    #pragma unroll 8
    for (int c = 0; c < DD; c += 4) {
        float4 wv = *(const float4*)(Wd + (size_t)p * DD + c);
        #pragma unroll
        for (int rr = 0; rr < 4; ++rr) {
            float4 xv = *(const float4*)(xs + (rg * 4 + rr) * DD + c);
            acc[rr] += wv.x * xv.x + wv.y * xv.y + wv.z * xv.z + wv.w * xv.w;
        }
    }
    const float bdp = bd[p];
    #pragma unroll
    for (int rr = 0; rr < 4; ++rr) {
        const int row = rg * 4 + rr;
        const float v = acc[rr] + bdp;
        xdl[row * 128 + p] = v;
        if (p < HP) qb[(size_t)(l0 + row) * HP + p] = __float2bfloat16(v);
        else        kf[(size_t)(l0 + row) * HP + (p - HP)] = v;
    }
    __syncthreads();

    const int h = tid & 127;
    const int sel = tid >> 7;           // 0 -> A2 (q part), 1 -> Bv (k part)
    float a8[8] = {0.f,0.f,0.f,0.f,0.f,0.f,0.f,0.f};
    #pragma unroll
    for (int c = 0; c < HP; c += 4) {
        float4 wv = *(const float4*)(W1 + (size_t)h * DP + HP + c);
        #pragma unroll
        for (int row = 0; row < 8; ++row) {
            float4 xv = *(const float4*)(xdl + row * 128 + (sel ? HP : 0) + c);
            a8[row] += wv.x * xv.x + wv.y * xv.y + wv.z * xv.z + wv.w * xv.w;
        }
    }
    if (sel == 0) {
        const float bb = b1[h];
        #pragma unroll
        for (int row = 0; row < 8; ++row)
            A2[(size_t)(l0 + row) * HH + h] = a8[row] + bb;
    } else {
        #pragma unroll
        for (int row = 0; row < 8; ++row)
            Bv[(size_t)(l0 + row) * HH + h] = a8[row];
    }
}

// ---------------------------------------------------------------------------
// Main: R4 structure exactly (W2s staged in LDS - the W2-from-global gather
// of R6/R7 cost ~28us: 512B-strided lanes, 32 VMEM gathers/thread).
// ONE change vs R4: __launch_bounds__(256, 3).
//   Occupancy is REGISTER-limited: total = archVGPR + 64 AGPR (acc[2][8]).
//   R4: 116+64=180 -> 2 waves/SIMD. Cap 3 waves -> total<=170 -> arch<=106,
//   only ~10 regs to shave (vs R6's fatal 64-cap). LDS 54272*3=162816<=160K ok
//   -> 3 blocks/CU.
// ---------------------------------------------------------------------------
__global__ __launch_bounds__(256, 3) void main_kernel(
    const float* __restrict__ W1, const float* __restrict__ W2,
    const float* __restrict__ b2, const float* __restrict__ lng,
    const float* __restrict__ lnb,
    const __hip_bfloat16* __restrict__ qb, const float* __restrict__ kf,
    const float* __restrict__ A2, const float* __restrict__ Bv,
    float* __restrict__ out)
{
    // [0, 18432) Mi[128][72] bf16 ; [18432, 36864) qt[128][72] bf16
    // hbuf[128][136] bf16 reuses [0,34816) after GEMM1 barrier
    // [36864, 54272) W2s[64][136] bf16
    __shared__ __align__(16) unsigned char smem[36864 + 17408];
    __bf16* Mi   = (__bf16*)smem;
    __bf16* qt   = (__bf16*)(smem + 18432);
    __bf16* hbuf = (__bf16*)smem;
    __bf16* W2s  = (__bf16*)(smem + 36864);

    const int tid  = threadIdx.x;
    const int lane = tid & 63;
    const int w    = tid >> 6;          // wave id 0..3
    const int lo   = lane & 15;
    const int g4   = lane >> 4;
    const int i    = blockIdx.y;
    const int j0   = blockIdx.x * 128;

    // ---- stage Mi = bf16(W1a * k_i)
    {
        const int hrow = tid >> 1;
        const int pb = (tid & 1) * 32;
        const float* w1r = W1 + (size_t)hrow * DP + pb;
        const float* kfr = kf + (size_t)i * HP + pb;
        #pragma unroll
        for (int m = 0; m < 4; ++m) {
            float4 w0 = *(const float4*)(w1r + m * 8);
            float4 w1v = *(const float4*)(w1r + m * 8 + 4);
            float4 k0 = *(const float4*)(kfr + m * 8);
            float4 k1 = *(const float4*)(kfr + m * 8 + 4);
            bf16x8 t;
            t[0] = (__bf16)(w0.x * k0.x); t[1] = (__bf16)(w0.y * k0.y);
            t[2] = (__bf16)(w0.z * k0.z); t[3] = (__bf16)(w0.w * k0.w);
            t[4] = (__bf16)(w1v.x * k1.x); t[5] = (__bf16)(w1v.y * k1.y);
            t[6] = (__bf16)(w1v.z * k1.z); t[7] = (__bf16)(w1v.w * k1.w);
            *(bf16x8*)&Mi[hrow * 72 + pb + m * 8] = t;
        }
    }
    // ---- stage qt (bf16 bit-copy)
    {
        const int jl = tid >> 1;
        const int pb = (tid & 1) * 32;
        const unsigned short* src = (const unsigned short*)qb + (size_t)(j0 + jl) * HP + pb;
        #pragma unroll
        for (int m = 0; m < 4; ++m) {
            uint4 v = *(const uint4*)(src + m * 8);
            *(uint4*)&qt[jl * 72 + pb + m * 8] = v;
        }
    }
    // ---- stage W2s (f32 -> bf16)
    {
        const int n = tid >> 2;
        const int hb0 = (tid & 3) * 32;
        const float* src = W2 + (size_t)n * HH + hb0;
        #pragma unroll
        for (int m = 0; m < 4; ++m) {
            float4 v0 = *(const float4*)(src + m * 8);
            float4 v1 = *(const float4*)(src + m * 8 + 4);
            bf16x8 t;
            t[0] = (__bf16)v0.x; t[1] = (__bf16)v0.y; t[2] = (__bf16)v0.z; t[3] = (__bf16)v0.w;
            t[4] = (__bf16)v1.x; t[5] = (__bf16)v1.y; t[6] = (__bf16)v1.z; t[7] = (__bf16)v1.w;
            *(bf16x8*)&W2s[n * 136 + hb0 + m * 8] = t;
        }
    }
    // per-lane constants
    float BvR[8], lgR[8], lbR[8];
    #pragma unroll
    for (int t = 0; t < 8; ++t) {
        const int h = t * 16 + lo;
        BvR[t] = Bv[(size_t)i * HH + h];
        lgR[t] = lng[h];
        lbR[t] = lnb[h];
    }
    float b2R[4];
    #pragma unroll
    for (int t = 0; t < 4; ++t) b2R[t] = b2[t * 16 + lo];

    __syncthreads();

    // ---- GEMM1: wave w owns rows [32w, 32w+32), all 128 h cols
    f32x4 acc[2][8];
    #pragma unroll
    for (int a = 0; a < 2; ++a)
        #pragma unroll
        for (int b = 0; b < 8; ++b)
            #pragma unroll
            for (int e = 0; e < 4; ++e) acc[a][b][e] = 0.f;

    #pragma unroll
    for (int kk = 0; kk < 2; ++kk) {
        bf16x8 af[2];
        #pragma unroll
        for (int mt = 0; mt < 2; ++mt) {
            const int jl = 32 * w + mt * 16 + lo;
            af[mt] = *(const bf16x8*)&qt[jl * 72 + kk * 32 + g4 * 8];
        }
        #pragma unroll
        for (int nt = 0; nt < 8; ++nt) {
            const int h = nt * 16 + lo;
            bf16x8 bfr = *(const bf16x8*)&Mi[h * 72 + kk * 32 + g4 * 8];
            #pragma unroll
            for (int mt = 0; mt < 2; ++mt)
                acc[mt][nt] = __builtin_amdgcn_mfma_f32_16x16x32_bf16(af[mt], bfr, acc[mt][nt], 0, 0, 0);
        }
    }

    __syncthreads();   // all waves done reading Mi/qt; hbuf may overwrite

    // ---- epilogue: v = acc + A2[j][h] - Bv[i][h]; gelu_exact; LN -> hbuf
    #pragma unroll
    for (int mt = 0; mt < 2; ++mt) {
        float s[4] = {0.f,0.f,0.f,0.f}, ss[4] = {0.f,0.f,0.f,0.f};
        #pragma unroll
        for (int nt = 0; nt < 8; ++nt) {
            const int h = nt * 16 + lo;
            #pragma unroll
            for (int r = 0; r < 4; ++r) {
                const int j = j0 + 32 * w + mt * 16 + g4 * 4 + r;
                float v = acc[mt][nt][r] + A2[(size_t)j * HH + h] - BvR[nt];
                float g = gelu_exact(v);
                acc[mt][nt][r] = g;
                s[r] += g; ss[r] += g * g;
            }
        }
        #pragma unroll
        for (int r = 0; r < 4; ++r) {
            float sv = s[r], sq = ss[r];
            #pragma unroll
            for (int m = 1; m < 16; m <<= 1) {
                sv += __shfl_xor(sv, m);
                sq += __shfl_xor(sq, m);
            }
            const float mu  = sv * (1.0f / 128.0f);
            const float var = sq * (1.0f / 128.0f) - mu * mu;
            const float rstd = rsqrtf(var + 1e-5f);
            const int jl = 32 * w + mt * 16 + g4 * 4 + r;
            #pragma unroll
            for (int nt = 0; nt < 8; ++nt) {
                const float hv = (acc[mt][nt][r] - mu) * rstd * lgR[nt] + lbR[nt];
                hbuf[jl * 136 + nt * 16 + lo] = (__bf16)hv;
            }
        }
    }
    __syncthreads();

    // ---- GEMM2: Out[128][64] = hbuf[128][128] @ W2s^T
    f32x4 acc2[2][4];
    #pragma unroll
    for (int a = 0; a < 2; ++a)
        #pragma unroll
        for (int b = 0; b < 4; ++b)
            #pragma unroll
            for (int e = 0; e < 4; ++e) acc2[a][b][e] = 0.f;

    #pragma unroll
    for (int kk = 0; kk < 4; ++kk) {
        bf16x8 af[2];
        #pragma unroll
        for (int mt = 0; mt < 2; ++mt) {
            const int jl = 32 * w + mt * 16 + lo;
            af[mt] = *(const bf16x8*)&hbuf[jl * 136 + kk * 32 + g4 * 8];
        }
        #pragma unroll
        for (int nt = 0; nt < 4; ++nt) {
            bf16x8 bfr = *(const bf16x8*)&W2s[(nt * 16 + lo) * 136 + kk * 32 + g4 * 8];
            #pragma unroll
            for (int mt = 0; mt < 2; ++mt)
                acc2[mt][nt] = __builtin_amdgcn_mfma_f32_16x16x32_bf16(af[mt], bfr, acc2[mt][nt], 0, 0, 0);
        }
    }

    // ---- store
    #pragma unroll
    for (int mt = 0; mt < 2; ++mt) {
        #pragma unroll
        for (int r = 0; r < 4; ++r) {
            const int j = j0 + 32 * w + mt * 16 + g4 * 4 + r;
            const size_t base = ((size_t)i * LL + j) * NB;
            #pragma unroll
            for (int nt = 0; nt < 4; ++nt)
                out[base + nt * 16 + lo] = acc2[mt][nt][r] + b2R[nt];
        }
    }
}

extern "C" void kernel_launch(void* const* d_in, const int* in_sizes, int n_in,
                              void* d_out, int out_size, void* d_ws, size_t ws_size,
                              hipStream_t stream) {
    const float* x   = (const float*)d_in[0];
    const float* Wd  = (const float*)d_in[1];
    const float* bd  = (const float*)d_in[2];
    const float* W1  = (const float*)d_in[3];
    const float* b1  = (const float*)d_in[4];
    const float* lng = (const float*)d_in[5];
    const float* lnb = (const float*)d_in[6];
    const float* W2  = (const float*)d_in[7];
    const float* b2  = (const float*)d_in[8];
    float* out = (float*)d_out;

    char* ws = (char*)d_ws;
    __hip_bfloat16* qb = (__hip_bfloat16*)ws;            //  98304 B
    float* kf = (float*)(ws + 98304);                    // 196608 B
    float* A2 = (float*)(ws + 294912);                   // 393216 B
    float* Bv = (float*)(ws + 688128);                   // 393216 B

    prep_kernel<<<96, 256, 0, stream>>>(x, Wd, bd, W1, b1, qb, kf, A2, Bv);
    dim3 grid(6, 768);
    main_kernel<<<grid, 256, 0, stream>>>(W1, W2, b2, lng, lnb, qb, kf, A2, Bv, out);
}

// Round 9
// 148.245 us; speedup vs baseline: 1.3334x; 1.0789x over previous
//
#include <hip/hip_runtime.h>
#include <hip/hip_bf16.h>

#define LL 768
#define DD 1024
#define DP 128
#define HP 64
#define HH 128
#define NB 64

typedef float f32x4 __attribute__((ext_vector_type(4)));
typedef __bf16 bf16x8 __attribute__((ext_vector_type(8)));

// Exact-erf GELU via Abramowitz-Stegun 7.1.26 (abs err <= 1.5e-7), branchless.
__device__ __forceinline__ float gelu_exact(float x) {
    const float z = fabsf(x) * 0.70710678118654752f;
    const float t = __builtin_amdgcn_rcpf(__builtin_fmaf(0.3275911f, z, 1.0f));
    float p = __builtin_fmaf(t, 1.061405429f, -1.453152027f);
    p = __builtin_fmaf(t, p, 1.421413741f);
    p = __builtin_fmaf(t, p, -0.284496736f);
    p = __builtin_fmaf(t, p, 0.254829592f);
    p = p * t;
    const float e = __expf(-z * z);
    const float erfz = __builtin_fmaf(-p, e, 1.0f);
    const float phi = 0.5f * (1.0f + copysignf(erfz, x));
    return x * phi;
}

// ---------------------------------------------------------------------------
// Prep: xd = x @ W_down^T + b_down (f32), then
//   qb[j][p]  = bf16(xd[j][p])          p<64
//   kf[i][p]  = xd[i][64+p]             f32
//   A2t[h][j] = sum_p W1[h][64+p]*q[j][p] + b1[h]   (TRANSPOSED for float4
//               epilogue loads: elements r=0..3 = consecutive j)
//   Bv[i][h]  = sum_p W1[h][64+p]*k[i][p]
// ---------------------------------------------------------------------------
__global__ __launch_bounds__(256) void prep_kernel(
    const float* __restrict__ x, const float* __restrict__ Wd,
    const float* __restrict__ bd, const float* __restrict__ W1,
    const float* __restrict__ b1,
    __hip_bfloat16* __restrict__ qb, float* __restrict__ kf,
    float* __restrict__ A2t, float* __restrict__ Bv)
{
    __shared__ __align__(16) float xs[8 * DD];
    __shared__ __align__(16) float xdl[8 * 128];
    const int tid = threadIdx.x;
    const int l0 = blockIdx.x * 8;

    const float4* xg = (const float4*)(x + (size_t)l0 * DD);
    float4* xs4 = (float4*)xs;
    for (int idx = tid; idx < 8 * DD / 4; idx += 256) xs4[idx] = xg[idx];
    __syncthreads();

    const int p = tid & 127;
    const int rg = tid >> 7;            // 0/1 -> rows rg*4 .. rg*4+3
    float acc[4] = {0.f, 0.f, 0.f, 0.f};
    #pragma unroll 8
    for (int c = 0; c < DD; c += 4) {
        float4 wv = *(const float4*)(Wd + (size_t)p * DD + c);
        #pragma unroll
        for (int rr = 0; rr < 4; ++rr) {
            float4 xv = *(const float4*)(xs + (rg * 4 + rr) * DD + c);
            acc[rr] += wv.x * xv.x + wv.y * xv.y + wv.z * xv.z + wv.w * xv.w;
        }
    }
    const float bdp = bd[p];
    #pragma unroll
    for (int rr = 0; rr < 4; ++rr) {
        const int row = rg * 4 + rr;
        const float v = acc[rr] + bdp;
        xdl[row * 128 + p] = v;
        if (p < HP) qb[(size_t)(l0 + row) * HP + p] = __float2bfloat16(v);
        else        kf[(size_t)(l0 + row) * HP + (p - HP)] = v;
    }
    __syncthreads();

    const int h = tid & 127;
    const int sel = tid >> 7;           // 0 -> A2t (q part), 1 -> Bv (k part)
    float a8[8] = {0.f,0.f,0.f,0.f,0.f,0.f,0.f,0.f};
    #pragma unroll
    for (int c = 0; c < HP; c += 4) {
        float4 wv = *(const float4*)(W1 + (size_t)h * DP + HP + c);
        #pragma unroll
        for (int row = 0; row < 8; ++row) {
            float4 xv = *(const float4*)(xdl + row * 128 + (sel ? HP : 0) + c);
            a8[row] += wv.x * xv.x + wv.y * xv.y + wv.z * xv.z + wv.w * xv.w;
        }
    }
    if (sel == 0) {
        const float bb = b1[h];
        #pragma unroll
        for (int row = 0; row < 8; ++row)
            A2t[(size_t)h * LL + (l0 + row)] = a8[row] + bb;
    } else {
        #pragma unroll
        for (int row = 0; row < 8; ++row)
            Bv[(size_t)(l0 + row) * HH + h] = a8[row];
    }
}

// ---------------------------------------------------------------------------
// Main (R8 base): block = (i, j-tile of 128), 4 waves, launch_bounds(256,3).
// Deltas vs R8:
//  (1) A2 epilogue loads: 64 scalar f32 -> 16 float4 via transposed A2t.
//  (2) LDS 54272 -> 53248: W2s staged AFTER GEMM1 barrier into the dead Mi
//      region; hbuf at qt+16KB. Same 3 barriers; W2 loads hide under epilogue.
// Layout: Mi [0,18432) ; qt [18432,36864) ; hbuf [18432,53248) (qt dead) ;
//         W2s [0,17408) (Mi dead, staged late)
// ---------------------------------------------------------------------------
__global__ __launch_bounds__(256, 3) void main_kernel(
    const float* __restrict__ W1, const float* __restrict__ W2,
    const float* __restrict__ b2, const float* __restrict__ lng,
    const float* __restrict__ lnb,
    const __hip_bfloat16* __restrict__ qb, const float* __restrict__ kf,
    const float* __restrict__ A2t, const float* __restrict__ Bv,
    float* __restrict__ out)
{
    __shared__ __align__(16) unsigned char smem[53248];
    __bf16* Mi   = (__bf16*)smem;                 // [128][72]
    __bf16* qt   = (__bf16*)(smem + 18432);       // [128][72]
    __bf16* hbuf = (__bf16*)(smem + 18432);       // [128][136] (over qt + fresh)
    __bf16* W2s  = (__bf16*)smem;                 // [64][136]  (over Mi, late)

    const int tid  = threadIdx.x;
    const int lane = tid & 63;
    const int w    = tid >> 6;          // wave id 0..3
    const int lo   = lane & 15;
    const int g4   = lane >> 4;
    const int i    = blockIdx.y;
    const int j0   = blockIdx.x * 128;

    // ---- stage Mi = bf16(W1a * k_i)
    {
        const int hrow = tid >> 1;
        const int pb = (tid & 1) * 32;
        const float* w1r = W1 + (size_t)hrow * DP + pb;
        const float* kfr = kf + (size_t)i * HP + pb;
        #pragma unroll
        for (int m = 0; m < 4; ++m) {
            float4 w0 = *(const float4*)(w1r + m * 8);
            float4 w1v = *(const float4*)(w1r + m * 8 + 4);
            float4 k0 = *(const float4*)(kfr + m * 8);
            float4 k1 = *(const float4*)(kfr + m * 8 + 4);
            bf16x8 t;
            t[0] = (__bf16)(w0.x * k0.x); t[1] = (__bf16)(w0.y * k0.y);
            t[2] = (__bf16)(w0.z * k0.z); t[3] = (__bf16)(w0.w * k0.w);
            t[4] = (__bf16)(w1v.x * k1.x); t[5] = (__bf16)(w1v.y * k1.y);
            t[6] = (__bf16)(w1v.z * k1.z); t[7] = (__bf16)(w1v.w * k1.w);
            *(bf16x8*)&Mi[hrow * 72 + pb + m * 8] = t;
        }
    }
    // ---- stage qt (bf16 bit-copy)
    {
        const int jl = tid >> 1;
        const int pb = (tid & 1) * 32;
        const unsigned short* src = (const unsigned short*)qb + (size_t)(j0 + jl) * HP + pb;
        #pragma unroll
        for (int m = 0; m < 4; ++m) {
            uint4 v = *(const uint4*)(src + m * 8);
            *(uint4*)&qt[jl * 72 + pb + m * 8] = v;
        }
    }
    // per-lane constants
    float BvR[8], lgR[8], lbR[8];
    #pragma unroll
    for (int t = 0; t < 8; ++t) {
        const int h = t * 16 + lo;
        BvR[t] = Bv[(size_t)i * HH + h];
        lgR[t] = lng[h];
        lbR[t] = lnb[h];
    }
    float b2R[4];
    #pragma unroll
    for (int t = 0; t < 4; ++t) b2R[t] = b2[t * 16 + lo];

    __syncthreads();

    // ---- GEMM1: wave w owns rows [32w, 32w+32), all 128 h cols
    f32x4 acc[2][8];
    #pragma unroll
    for (int a = 0; a < 2; ++a)
        #pragma unroll
        for (int b = 0; b < 8; ++b)
            #pragma unroll
            for (int e = 0; e < 4; ++e) acc[a][b][e] = 0.f;

    #pragma unroll
    for (int kk = 0; kk < 2; ++kk) {
        bf16x8 af[2];
        #pragma unroll
        for (int mt = 0; mt < 2; ++mt) {
            const int jl = 32 * w + mt * 16 + lo;
            af[mt] = *(const bf16x8*)&qt[jl * 72 + kk * 32 + g4 * 8];
        }
        #pragma unroll
        for (int nt = 0; nt < 8; ++nt) {
            const int h = nt * 16 + lo;
            bf16x8 bfr = *(const bf16x8*)&Mi[h * 72 + kk * 32 + g4 * 8];
            #pragma unroll
            for (int mt = 0; mt < 2; ++mt)
                acc[mt][nt] = __builtin_amdgcn_mfma_f32_16x16x32_bf16(af[mt], bfr, acc[mt][nt], 0, 0, 0);
        }
    }

    __syncthreads();   // Mi/qt dead; W2s + hbuf regions free to write

    // ---- stage W2s (f32 -> bf16) into dead Mi region; loads hide under epilogue
    {
        const int n = tid >> 2;
        const int hb0 = (tid & 3) * 32;
        const float* src = W2 + (size_t)n * HH + hb0;
        #pragma unroll
        for (int m = 0; m < 4; ++m) {
            float4 v0 = *(const float4*)(src + m * 8);
            float4 v1 = *(const float4*)(src + m * 8 + 4);
            bf16x8 t;
            t[0] = (__bf16)v0.x; t[1] = (__bf16)v0.y; t[2] = (__bf16)v0.z; t[3] = (__bf16)v0.w;
            t[4] = (__bf16)v1.x; t[5] = (__bf16)v1.y; t[6] = (__bf16)v1.z; t[7] = (__bf16)v1.w;
            *(bf16x8*)&W2s[n * 136 + hb0 + m * 8] = t;
        }
    }

    // ---- epilogue: v = acc + A2t[h][j] - Bv[i][h]; gelu_exact; LN -> hbuf
    #pragma unroll
    for (int mt = 0; mt < 2; ++mt) {
        const int jb = j0 + 32 * w + mt * 16 + g4 * 4;
        f32x4 a2v[8];
        #pragma unroll
        for (int nt = 0; nt < 8; ++nt)
            a2v[nt] = *(const f32x4*)&A2t[(size_t)(nt * 16 + lo) * LL + jb];

        float s[4] = {0.f,0.f,0.f,0.f}, ss[4] = {0.f,0.f,0.f,0.f};
        #pragma unroll
        for (int nt = 0; nt < 8; ++nt) {
            #pragma unroll
            for (int r = 0; r < 4; ++r) {
                float v = acc[mt][nt][r] + a2v[nt][r] - BvR[nt];
                float g = gelu_exact(v);
                acc[mt][nt][r] = g;
                s[r] += g; ss[r] += g * g;
            }
        }
        #pragma unroll
        for (int r = 0; r < 4; ++r) {
            float sv = s[r], sq = ss[r];
            #pragma unroll
            for (int m = 1; m < 16; m <<= 1) {
                sv += __shfl_xor(sv, m);
                sq += __shfl_xor(sq, m);
            }
            const float mu  = sv * (1.0f / 128.0f);
            const float var = sq * (1.0f / 128.0f) - mu * mu;
            const float rstd = rsqrtf(var + 1e-5f);
            const int jl = 32 * w + mt * 16 + g4 * 4 + r;
            #pragma unroll
            for (int nt = 0; nt < 8; ++nt) {
                const float hv = (acc[mt][nt][r] - mu) * rstd * lgR[nt] + lbR[nt];
                hbuf[jl * 136 + nt * 16 + lo] = (__bf16)hv;
            }
        }
    }
    __syncthreads();   // hbuf + W2s complete before GEMM2 reads

    // ---- GEMM2: Out[128][64] = hbuf[128][128] @ W2s^T
    f32x4 acc2[2][4];
    #pragma unroll
    for (int a = 0; a < 2; ++a)
        #pragma unroll
        for (int b = 0; b < 4; ++b)
            #pragma unroll
            for (int e = 0; e < 4; ++e) acc2[a][b][e] = 0.f;

    #pragma unroll
    for (int kk = 0; kk < 4; ++kk) {
        bf16x8 af[2];
        #pragma unroll
        for (int mt = 0; mt < 2; ++mt) {
            const int jl = 32 * w + mt * 16 + lo;
            af[mt] = *(const bf16x8*)&hbuf[jl * 136 + kk * 32 + g4 * 8];
        }
        #pragma unroll
        for (int nt = 0; nt < 4; ++nt) {
            bf16x8 bfr = *(const bf16x8*)&W2s[(nt * 16 + lo) * 136 + kk * 32 + g4 * 8];
            #pragma unroll
            for (int mt = 0; mt < 2; ++mt)
                acc2[mt][nt] = __builtin_amdgcn_mfma_f32_16x16x32_bf16(af[mt], bfr, acc2[mt][nt], 0, 0, 0);
        }
    }

    // ---- store
    #pragma unroll
    for (int mt = 0; mt < 2; ++mt) {
        #pragma unroll
        for (int r = 0; r < 4; ++r) {
            const int j = j0 + 32 * w + mt * 16 + g4 * 4 + r;
            const size_t base = ((size_t)i * LL + j) * NB;
            #pragma unroll
            for (int nt = 0; nt < 4; ++nt)
                out[base + nt * 16 + lo] = acc2[mt][nt][r] + b2R[nt];
        }
    }
}

extern "C" void kernel_launch(void* const* d_in, const int* in_sizes, int n_in,
                              void* d_out, int out_size, void* d_ws, size_t ws_size,
                              hipStream_t stream) {
    const float* x   = (const float*)d_in[0];
    const float* Wd  = (const float*)d_in[1];
    const float* bd  = (const float*)d_in[2];
    const float* W1  = (const float*)d_in[3];
    const float* b1  = (const float*)d_in[4];
    const float* lng = (const float*)d_in[5];
    const float* lnb = (const float*)d_in[6];
    const float* W2  = (const float*)d_in[7];
    const float* b2  = (const float*)d_in[8];
    float* out = (float*)d_out;

    char* ws = (char*)d_ws;
    __hip_bfloat16* qb = (__hip_bfloat16*)ws;            //  98304 B
    float* kf  = (float*)(ws + 98304);                   // 196608 B
    float* A2t = (float*)(ws + 294912);                  // 393216 B  [128 h][768 j]
    float* Bv  = (float*)(ws + 688128);                  // 393216 B

    prep_kernel<<<96, 256, 0, stream>>>(x, Wd, bd, W1, b1, qb, kf, A2t, Bv);
    dim3 grid(6, 768);
    main_kernel<<<grid, 256, 0, stream>>>(W1, W2, b2, lng, lnb, qb, kf, A2t, Bv, out);
}